// Round 1
// baseline (196.703 us; speedup 1.0000x reference)
//
#include <hip/hip_runtime.h>

typedef _Float16 f16;
typedef f16 f16x8 __attribute__((ext_vector_type(8)));
typedef float f32x4 __attribute__((ext_vector_type(4)));
typedef unsigned short u16;

// async global->LDS, 16B per lane. dst = wave-uniform base + lane*16.
__device__ __forceinline__ void glds16(const void* g, void* l) {
  __builtin_amdgcn_global_load_lds(
      (const __attribute__((address_space(1))) unsigned*)g,
      (__attribute__((address_space(3))) unsigned*)l, 16, 0, 0);
}

// ---------------------------------------------------------------------------
// Swizzled fp16 layouts (16B = 8-f16 units, BK=32 K-tiles), M-block = 48:
// X [24576,256]: q -> b=q/48, m=q%48; c -> kt=c>>5, g=(c>>3)&3, j=c&7;
//   u = m*4 + (g ^ ((m>>1)&3));  elem off = b*12288 + kt*1536 + u*8 + j
// W [256,K]: n,c -> kt=c>>5, g=(c>>3)&3, j=c&7; u = n*4 + (g^((n>>1)&3));
//   off = kt*8192 + u*8 + j
// H (LDS, 48x256): m,k -> g=k>>3; u = m*32 + (g ^ ((m>>1)&7))
// ---------------------------------------------------------------------------

// ---------------------------------------------------------------------------
// Column decode table: col -> (src scalar idx, freq, kind)
// kind: 0 raw, 1 sin, 2 cos, 3 zero.  enc = src | f<<5 | kind<<9
// ---------------------------------------------------------------------------
struct FT {
  u16 v[256];
  static constexpr u16 enc(int s, int f, int k) {
    return (u16)(s | (f << 5) | (k << 9));
  }
  constexpr void p3(int base, int F, int src) {
    v[base + 0] = enc(src + 0, 0, 0);
    v[base + 1] = enc(src + 1, 0, 0);
    v[base + 2] = enc(src + 2, 0, 0);
    for (int f = 0; f < F; ++f)
      for (int r = 0; r < 6; ++r) {
        int comp = (r < 3) ? r : r - 3;
        v[base + 3 + f * 6 + r] = enc(src + comp, f, (r < 3) ? 1 : 2);
      }
  }
  constexpr void p1(int base, int F, int src) {
    v[base] = enc(src, 0, 0);
    for (int f = 0; f < F; ++f) {
      v[base + 1 + 2 * f] = enc(src, f, 1);
      v[base + 2 + 2 * f] = enc(src, f, 2);
    }
  }
  constexpr FT() : v{} {
    p3(0, 10, 0);     // hit_pos_emb   (q)          [0..62]
    p1(63, 4, 3);     // density_emb                [63..71]
    p3(72, 10, 4);    // smoothed_emb  (sp)         [72..134]
    p3(135, 10, 7);   // var_emb       (var)        [135..197]
    p3(198, 4, 10);   // hit_dir_emb   (ray dir)    [198..224]
    p3(225, 4, 13);   // dirs_emb      (dir)        [225..251]
    v[252] = enc(16, 0, 0);  // normals
    v[253] = enc(17, 0, 0);
    v[254] = enc(18, 0, 0);
    v[255] = enc(0, 0, 3);   // pad col
  }
};
__constant__ FT ftab = FT();

// ---------------------------------------------------------------------------
// Uniform grid for ball query: 5x5x5 cells, cell size 0.2 = 2*RADIUS.
// g_sorted: particles bucketed by cell (order within cell ARBITRARY —
// first-16-by-index selection is done via threshold search, not storage order).
// ---------------------------------------------------------------------------
__device__ float4 g_sorted[4096];   // x,y,z, w = bitcast(original index)
__device__ int    g_cellStart[126];

__global__ __launch_bounds__(1024) void build_grid(const float* __restrict__ parts)
{
  __shared__ int cnt[125];
  __shared__ int pos[126];
  const int tid = threadIdx.x;
  if (tid < 125) cnt[tid] = 0;
  __syncthreads();

  float px[4], py[4], pz[4];
  int cd[4];
  #pragma unroll
  for (int t = 0; t < 4; ++t) {
    int i = tid + t * 1024;
    float x = parts[3 * i], y = parts[3 * i + 1], z = parts[3 * i + 2];
    int cx = min(max((int)(x * 5.0f), 0), 4);
    int cy = min(max((int)(y * 5.0f), 0), 4);
    int cz = min(max((int)(z * 5.0f), 0), 4);
    cd[t] = (cz * 5 + cy) * 5 + cx;
    px[t] = x; py[t] = y; pz[t] = z;
    atomicAdd(&cnt[cd[t]], 1);
  }
  __syncthreads();
  if (tid == 0) {
    int s = 0;
    for (int c = 0; c < 125; ++c) { pos[c] = s; s += cnt[c]; }
    pos[125] = s;
  }
  __syncthreads();
  if (tid < 126) g_cellStart[tid] = pos[tid];
  __syncthreads();                       // copy done before scatter mutates pos
  #pragma unroll
  for (int t = 0; t < 4; ++t) {
    int i = tid + t * 1024;
    int p = atomicAdd(&pos[cd[t]], 1);
    g_sorted[p] = make_float4(px[t], py[t], pz[t], __int_as_float(i));
  }
}

// ---------------------------------------------------------------------------
// Kernel 1: weight prep fp32 -> fp16, BK=32 swizzled layout.
// ---------------------------------------------------------------------------
__global__ __launch_bounds__(256) void prep_weights(
    const float* __restrict__ W0, const float* __restrict__ W1,
    const float* __restrict__ W2,
    f16* __restrict__ w0f, f16* __restrict__ w1f, f16* __restrict__ w2f)
{
  int i = blockIdx.x * 256 + threadIdx.x;   // 0 .. 262143
  float v; f16* pf; int n, c;
  if (i < 131072) {
    n = i >> 9; c = i & 511;
    v = (c < 255) ? W0[n * 511 + c] : ((c == 255) ? 0.0f : W0[n * 511 + (c - 1)]);
    pf = w0f;
  } else if (i < 196608) {
    int j = i - 131072; n = j >> 8; c = j & 255; v = W1[j]; pf = w1f;
  } else {
    int j = i - 196608; n = j >> 8; c = j & 255; v = W2[j]; pf = w2f;
  }
  int kt = c >> 5, g = (c >> 3) & 3, jj = c & 7;
  int u = n * 4 + (g ^ ((n >> 1) & 3));
  pf[kt * 8192 + u * 8 + jj] = (f16)v;
}

// ---------------------------------------------------------------------------
// Kernel 2: grid-accelerated ball query + features -> swizzled fp16 X.
// 1 wave/query, 16 queries/block. 2x2x2 cell neighborhood (~260 candidates
// vs 4096 brute force). First-16-by-index via binary-searched index threshold.
// Wave-uniform fallback to brute scan if neighborhood is abnormal.
// ---------------------------------------------------------------------------
#define MAXCH 6   // up to 384 candidate slots per query

__global__ __launch_bounds__(1024) void feat_kernel(
    const float* __restrict__ points, const float* __restrict__ normals,
    const float* __restrict__ parts, const float* __restrict__ rays,
    const float* __restrict__ ro, f16* __restrict__ Xf)
{
  __shared__ float sdata[16][20];

  const int tid = threadIdx.x;
  const int lane = tid & 63, wv = tid >> 6;
  const int q = blockIdx.x * 16 + wv;
  const float qx = points[3 * q], qy = points[3 * q + 1], qz = points[3 * q + 2];
  const float RQ = 0.1f * 0.1f;

  int nAcc = 0;
  float sdx = 0, sdy = 0, sdz = 0;
  float s2x = 0, s2y = 0, s2z = 0;
  float sw = 0, swx = 0, swy = 0, swz = 0;

  // ---- candidate cell ranges (conservative margin; superset is safe) ----
  const float MRG = 0.1001f;
  int ax0 = min(max((int)floorf((qx - MRG) * 5.0f), 0), 4);
  int ax1 = min(max((int)floorf((qx + MRG) * 5.0f), 0), 4);
  int ay0 = min(max((int)floorf((qy - MRG) * 5.0f), 0), 4);
  int ay1 = min(max((int)floorf((qy + MRG) * 5.0f), 0), 4);
  int az0 = min(max((int)floorf((qz - MRG) * 5.0f), 0), 4);
  int az1 = min(max((int)floorf((qz + MRG) * 5.0f), 0), 4);
  bool fb = (ax1 - ax0 > 1) || (ay1 - ay0 > 1) || (az1 - az0 > 1);

  // lanes (mod 8) each own one of the 8 neighborhood cells
  int jj = lane & 7;
  int bx = jj & 1, by = (jj >> 1) & 1, bz = jj >> 2;
  int cx = bx ? ax1 : ax0;
  int cy = by ? ay1 : ay0;
  int cz = bz ? az1 : az0;
  bool val8 = (!bx || ax1 > ax0) && (!by || ay1 > ay0) && (!bz || az1 > az0);
  int cid = (cz * 5 + cy) * 5 + cx;
  int st = g_cellStart[cid], en = g_cellStart[cid + 1];
  int cn = val8 ? (en - st) : 0;

  int nk[8], sk[8];
  #pragma unroll
  for (int k = 0; k < 8; ++k) {
    nk[k] = __shfl(cn, k, 64);
    sk[k] = __shfl(st, k, 64);
  }
  int pk[8]; pk[0] = 0;
  #pragma unroll
  for (int k = 1; k < 8; ++k) pk[k] = pk[k - 1] + nk[k - 1];
  const int C = pk[7] + nk[7];
  int bk[8];
  #pragma unroll
  for (int k = 0; k < 8; ++k) bk[k] = sk[k] - pk[k];
  if (C > MAXCH * 64) fb = true;

  if (!fb) {
    float4 sv[MAXCH];
    unsigned long long hm[MAXCH];
    #pragma unroll
    for (int ch = 0; ch < MAXCH; ++ch) {
      int s = ch * 64 + lane;
      int g = bk[0];
      #pragma unroll
      for (int k = 1; k < 8; ++k) g = (s >= pk[k]) ? bk[k] : g;
      float4 pt = g_sorted[min(g + s, 4095)];
      if (s >= C) {                      // sentinel: never hits, idx = +inf
        pt.x = 1e9f; pt.y = 1e9f; pt.z = 1e9f;
        pt.w = __int_as_float(0x7fffffff);
      }
      sv[ch] = pt;
      float ex = pt.x - qx, ey = pt.y - qy, ez = pt.z - qz;
      float d2 = __fadd_rn(__fadd_rn(__fmul_rn(ex, ex), __fmul_rn(ey, ey)),
                           __fmul_rn(ez, ez));
      hm[ch] = __ballot(d2 < RQ);
    }

    int N = 0;
    #pragma unroll
    for (int ch = 0; ch < MAXCH; ++ch) N += __popcll(hm[ch]);

    // threshold = 16th-smallest hit index (accept idx <= thr)
    int thr = 0x7fffffff;
    if (N > 16) {
      int lo = 0, hi = 4095;
      while (lo < hi) {
        int mid = (lo + hi) >> 1;
        int c = 0;
        #pragma unroll
        for (int ch = 0; ch < MAXCH; ++ch)
          c += __popcll(hm[ch] & __ballot(__float_as_int(sv[ch].w) <= mid));
        if (c >= 16) hi = mid; else lo = mid + 1;
      }
      thr = lo;
    }

    #pragma unroll
    for (int ch = 0; ch < MAXCH; ++ch) {
      float4 pt = sv[ch];
      float ex = pt.x - qx, ey = pt.y - qy, ez = pt.z - qz;
      float d2 = __fadd_rn(__fadd_rn(__fmul_rn(ex, ex), __fmul_rn(ey, ey)),
                           __fmul_rn(ez, ez));
      if (d2 < RQ && __float_as_int(pt.w) <= thr) {
        nAcc++;
        sdx += ex; sdy += ey; sdz += ez;
        s2x += ex * ex; s2y += ey * ey; s2z += ez * ez;
        float dn = sqrtf(d2);
        float t = dn * 10.0f;
        float w = fmaxf(1.0f - t * t * t, 0.0f);
        sw += w; swx += w * pt.x; swy += w * pt.y; swz += w * pt.z;
      }
    }
  } else {
    // brute-force scan in index order (rare; wave-uniform)
    int total = 0;
    for (int jr = 0; jr < 64; ++jr) {
      int pi = jr * 64 + lane;
      float x = parts[3 * pi], y = parts[3 * pi + 1], z = parts[3 * pi + 2];
      float ex = x - qx, ey = y - qy, ez = z - qz;
      float d2 = __fadd_rn(__fadd_rn(__fmul_rn(ex, ex), __fmul_rn(ey, ey)),
                           __fmul_rn(ez, ez));
      bool hit = d2 < RQ;
      unsigned long long m = __ballot(hit);
      int pos = __builtin_amdgcn_mbcnt_hi((unsigned)(m >> 32),
                __builtin_amdgcn_mbcnt_lo((unsigned)m, 0u));
      if (hit && (total + pos < 16)) {
        nAcc++;
        sdx += ex; sdy += ey; sdz += ez;
        s2x += ex * ex; s2y += ey * ey; s2z += ez * ez;
        float dn = sqrtf(d2);
        float t = dn * 10.0f;
        float w = fmaxf(1.0f - t * t * t, 0.0f);
        sw += w; swx += w * x; swy += w * y; swz += w * z;
      }
      total += __popcll(m);
      if (total >= 16) break;
    }
  }

  #define WRED(x) { _Pragma("unroll") for (int o = 32; o; o >>= 1) x += __shfl_xor(x, o, 64); }
  float fn = (float)nAcc;
  WRED(fn); WRED(sdx); WRED(sdy); WRED(sdz);
  WRED(s2x); WRED(s2y); WRED(s2z);
  WRED(sw); WRED(swx); WRED(swy); WRED(swz);
  #undef WRED

  float tq = sqrtf(qx * qx + qy * qy + qz * qz) * 10.0f;
  float wpad = fmaxf(1.0f - tq * tq * tq, 0.0f);
  float density = sw + (16.0f - fn) * wpad;
  float invd = 1.0f / (density + 1e-12f);
  float spx = swx * invd, spy = swy * invd, spz = swz * invd;

  float invn = 1.0f / (fn + 1e-12f);
  float mx = sdx * invn, my = sdy * invn, mz = sdz * invn;
  float vx = fmaxf((s2x - 2.0f * mx * sdx + fn * mx * mx) * invn, 0.0f);
  float vy = fmaxf((s2y - 2.0f * my * sdy + fn * my * my) * invn, 0.0f);
  float vz = fmaxf((s2z - 2.0f * mz * sdz + fn * mz * mz) * invn, 0.0f);

  float dxx = spx - ro[0], dyy = spy - ro[1], dzz = spz - ro[2];
  float il = 1.0f / sqrtf(dxx * dxx + dyy * dyy + dzz * dzz);

  if (lane == 0) {
    float* s = sdata[wv];
    s[0] = qx; s[1] = qy; s[2] = qz; s[3] = density;
    s[4] = spx; s[5] = spy; s[6] = spz;
    s[7] = vx; s[8] = vy; s[9] = vz;
    int r = q / 48;
    s[10] = rays[6 * r + 3]; s[11] = rays[6 * r + 4]; s[12] = rays[6 * r + 5];
    s[13] = dxx * il; s[14] = dyy * il; s[15] = dzz * il;
    s[16] = normals[3 * q]; s[17] = normals[3 * q + 1]; s[18] = normals[3 * q + 2];
  }
  __syncthreads();

  const int b = q / 48, m48 = q % 48;
  const size_t base = (size_t)b * 12288;
  #pragma unroll
  for (int it = 0; it < 4; ++it) {
    int c = it * 64 + lane;
    int e = ftab.v[c];
    float sv_ = sdata[wv][e & 31];
    float arg = sv_ * (float)(1 << ((e >> 5) & 15));
    float sn, cs;
    sincosf(arg, &sn, &cs);
    int kind = e >> 9;
    float val = (kind == 0) ? sv_ : (kind == 1 ? sn : (kind == 2 ? cs : 0.0f));
    int kt = c >> 5, g = (c >> 3) & 3, j = c & 7;
    int u = m48 * 4 + (g ^ ((m48 >> 1) & 3));
    Xf[base + kt * 1536 + u * 8 + j] = (f16)val;
  }
}

// ---------------------------------------------------------------------------
// Kernel 3: fused 3-layer fp16 MFMA MLP + final 256->3 + sigmoid (unchanged).
// ---------------------------------------------------------------------------
__global__ __launch_bounds__(256, 2) void fused_mlp(
    const f16* __restrict__ Xf, const float* __restrict__ fvec,
    const f16* __restrict__ w0f, const f16* __restrict__ w1f,
    const f16* __restrict__ w2f,
    const float* __restrict__ b0, const float* __restrict__ b1,
    const float* __restrict__ b2,
    const float* __restrict__ W3, const float* __restrict__ b3,
    float* __restrict__ out)
{
  extern __shared__ char lds[];
  f16* Hf    = (f16*)lds;                 // 24576 B
  f16* Bs    = (f16*)(lds + 24576);       // 16384 B
  f16* Ah_st = (f16*)lds;                 // 3072 B (L0 only)
  float* w3s = (float*)(lds + 24576);

  const int tid = threadIdx.x, lane = tid & 63, wn = tid >> 6;
  const int l15 = lane & 15, l4 = lane >> 4;
  const int blk = blockIdx.x;

  if (blk & 1) __builtin_amdgcn_s_sleep(8);   // de-phase co-resident blocks

  f32x4 acc[3][4];

  const f16* Xft = Xf + (size_t)blk * 12288;

  auto stageB = [&](const f16* wf, int kt) {
    #pragma unroll
    for (int s = 0; s < 4; ++s) {
      int ch = wn + s * 4;                // 0..15, 1 KB chunks
      glds16(wf + kt * 8192 + ch * 512 + lane * 8, Bs + ch * 512 + lane * 8);
    }
  };
  auto stageA = [&](int kt) {
    if (kt < 8) {
      if (wn < 3)
        glds16(Xft + kt * 1536 + wn * 512 + lane * 8, Ah_st + wn * 512 + lane * 8);
    } else {
      if (tid < 192) {
        int m = tid >> 2, g = tid & 3;
        const float* src = fvec + (size_t)(blk * 48 + m) * 256 + (kt - 8) * 32 + g * 8;
        float4 v0 = ((const float4*)src)[0];
        float4 v1 = ((const float4*)src)[1];
        f16 hs[8] = {(f16)v0.x, (f16)v0.y, (f16)v0.z, (f16)v0.w,
                     (f16)v1.x, (f16)v1.y, (f16)v1.z, (f16)v1.w};
        int u = m * 4 + (g ^ ((m >> 1) & 3));
        *(uint4*)(Ah_st + u * 8) = *(uint4*)hs;
      }
    }
  };
  auto bfrags = [&](f16x8* bf) {
    #pragma unroll
    for (int j = 0; j < 4; ++j) {
      int n = wn * 64 + j * 16 + l15;
      int u = n * 4 + (l4 ^ ((n >> 1) & 3));
      bf[j] = __builtin_bit_cast(f16x8, *(const uint4*)(Bs + u * 8));
    }
  };
  auto mfmas = [&](f16x8* af, f16x8* bf) {
    #pragma unroll
    for (int i = 0; i < 3; ++i)
      #pragma unroll
      for (int j = 0; j < 4; ++j)
        acc[i][j] = __builtin_amdgcn_mfma_f32_16x16x32_f16(af[i], bf[j], acc[i][j], 0, 0, 0);
  };
  auto epilogue = [&](const float* bias_) {
    float bv[4];
    #pragma unroll
    for (int j = 0; j < 4; ++j) bv[j] = bias_[wn * 64 + j * 16 + l15];
    #pragma unroll
    for (int i = 0; i < 3; ++i) {
      #pragma unroll
      for (int r = 0; r < 4; ++r) {
        int m = i * 16 + l4 * 4 + r;
        #pragma unroll
        for (int j = 0; j < 4; ++j) {
          int n = wn * 64 + j * 16 + l15;
          float v = fmaxf(acc[i][j][r] + bv[j], 0.0f);
          int u = m * 32 + ((n >> 3) ^ ((m >> 1) & 7));
          Hf[u * 8 + (n & 7)] = (f16)v;
        }
      }
    }
  };

  // ======================= L0: K=512 (8 kt from X, 8 from fvec) ============
  #pragma unroll
  for (int i = 0; i < 3; ++i)
    #pragma unroll
    for (int j = 0; j < 4; ++j) acc[i][j] = (f32x4){0, 0, 0, 0};

  stageA(0);
  stageB(w0f, 0);
  for (int kt = 0; kt < 16; ++kt) {
    __syncthreads();                       // drain stage(kt)
    f16x8 af[3], bf[4];
    #pragma unroll
    for (int i = 0; i < 3; ++i) {
      int m = i * 16 + l15;
      int u = m * 4 + (l4 ^ ((m >> 1) & 3));
      af[i] = __builtin_bit_cast(f16x8, *(const uint4*)(Ah_st + u * 8));
    }
    bfrags(bf);
    __syncthreads();                       // all reads in regs
    if (kt < 15) { stageA(kt + 1); stageB(w0f, kt + 1); }
    mfmas(af, bf);
  }
  epilogue(b0);

  // ======================= L1, L2: K=256, A from Hf ========================
  #pragma unroll 1
  for (int layer = 0; layer < 2; ++layer) {
    const f16* wf = layer ? w2f : w1f;
    #pragma unroll
    for (int i = 0; i < 3; ++i)
      #pragma unroll
      for (int j = 0; j < 4; ++j) acc[i][j] = (f32x4){0, 0, 0, 0};

    stageB(wf, 0);
    for (int kt = 0; kt < 8; ++kt) {
      __syncthreads();                     // kt=0 also fences epilogue H writes
      f16x8 af[3], bf[4];
      #pragma unroll
      for (int i = 0; i < 3; ++i) {
        int m = i * 16 + l15;
        int g = kt * 4 + l4;
        int u = m * 32 + (g ^ ((m >> 1) & 7));
        af[i] = __builtin_bit_cast(f16x8, *(const uint4*)(Hf + u * 8));
      }
      bfrags(bf);
      __syncthreads();
      if (kt < 7) stageB(wf, kt + 1);
      mfmas(af, bf);
    }
    epilogue(layer ? b2 : b1);
  }

  // ======================= final: 256 -> 3 + sigmoid =======================
  __syncthreads();                         // H complete, B region free
  for (int i = tid; i < 768; i += 256) w3s[i] = W3[i];
  __syncthreads();

  const float B30 = b3[0], B31 = b3[1], B32 = b3[2];
  #pragma unroll 1
  for (int rr = 0; rr < 12; ++rr) {
    int m = wn * 12 + rr;
    int g = lane >> 1, j0 = (lane & 1) * 4;
    int u = m * 32 + (g ^ ((m >> 1) & 7));
    uint2 pk = *(const uint2*)(Hf + u * 8 + j0);
    f16 h4[4];
    *(uint2*)h4 = pk;
    float h0 = (float)h4[0], h1 = (float)h4[1], h2 = (float)h4[2], h3 = (float)h4[3];
    int kc = lane * 4;
    float4 wa = *(const float4*)(w3s + kc);
    float4 wb = *(const float4*)(w3s + 256 + kc);
    float4 wc = *(const float4*)(w3s + 512 + kc);
    float p0 = fmaf(h3, wa.w, fmaf(h2, wa.z, fmaf(h1, wa.y, h0 * wa.x)));
    float p1 = fmaf(h3, wb.w, fmaf(h2, wb.z, fmaf(h1, wb.y, h0 * wb.x)));
    float p2 = fmaf(h3, wc.w, fmaf(h2, wc.z, fmaf(h1, wc.y, h0 * wc.x)));
    #pragma unroll
    for (int o = 32; o; o >>= 1) {
      p0 += __shfl_xor(p0, o, 64);
      p1 += __shfl_xor(p1, o, 64);
      p2 += __shfl_xor(p2, o, 64);
    }
    if (lane == 0) {
      size_t ro_ = (size_t)(blk * 48 + m) * 3;
      out[ro_ + 0] = 1.0f / (1.0f + expf(-(p0 + B30)));
      out[ro_ + 1] = 1.0f / (1.0f + expf(-(p1 + B31)));
      out[ro_ + 2] = 1.0f / (1.0f + expf(-(p2 + B32)));
    }
  }
}

// ---------------------------------------------------------------------------
extern "C" void kernel_launch(void* const* d_in, const int* in_sizes, int n_in,
                              void* d_out, int out_size, void* d_ws, size_t ws_size,
                              hipStream_t stream) {
  const float* points  = (const float*)d_in[0];
  const float* normals = (const float*)d_in[1];
  const float* fvec    = (const float*)d_in[3];
  const float* parts   = (const float*)d_in[5];
  const float* rays    = (const float*)d_in[6];
  const float* ro      = (const float*)d_in[7];
  const float* W0 = (const float*)d_in[8];
  const float* b0 = (const float*)d_in[9];
  const float* W1 = (const float*)d_in[10];
  const float* b1 = (const float*)d_in[11];
  const float* W2 = (const float*)d_in[12];
  const float* b2 = (const float*)d_in[13];
  const float* W3 = (const float*)d_in[14];
  const float* b3 = (const float*)d_in[15];

  char* ws = (char*)d_ws;
  f16* Xf  = (f16*)(ws);                    // [24576,256] fp16 swizzled, 12.58 MB
  f16* w0f = (f16*)(ws + 12582912);         // 262144 B
  f16* w1f = (f16*)(ws + 12845056);         // 131072 B
  f16* w2f = (f16*)(ws + 12976128);         // 131072 B
  float* out = (float*)d_out;

  (void)hipFuncSetAttribute((const void*)fused_mlp,
                            hipFuncAttributeMaxDynamicSharedMemorySize, 40960);

  build_grid<<<1, 1024, 0, stream>>>(parts);
  prep_weights<<<1024, 256, 0, stream>>>(W0, W1, W2, w0f, w1f, w2f);
  feat_kernel<<<1536, 1024, 0, stream>>>(points, normals, parts, rays, ro, Xf);
  fused_mlp<<<512, 256, 40960, stream>>>(Xf, fvec, w0f, w1f, w2f,
                                         b0, b1, b2, W3, b3, out);
}

// Round 2
// 166.063 us; speedup vs baseline: 1.1845x; 1.1845x over previous
//
#include <hip/hip_runtime.h>

typedef _Float16 f16;
typedef f16 f16x8 __attribute__((ext_vector_type(8)));
typedef float f32x4 __attribute__((ext_vector_type(4)));
typedef unsigned short u16;

// async global->LDS, 16B per lane. dst = wave-uniform base + lane*16.
__device__ __forceinline__ void glds16(const void* g, void* l) {
  __builtin_amdgcn_global_load_lds(
      (const __attribute__((address_space(1))) unsigned*)g,
      (__attribute__((address_space(3))) unsigned*)l, 16, 0, 0);
}

// ---------------------------------------------------------------------------
// Swizzled fp16 layouts (16B = 8-f16 units, BK=32 K-tiles), M-block = 48:
// X [24576,256]: q -> b=q/48, m=q%48; c -> kt=c>>5, g=(c>>3)&3, j=c&7;
//   u = m*4 + (g ^ ((m>>1)&3));  elem off = b*12288 + kt*1536 + u*8 + j
// W [256,K]: n,c -> kt=c>>5, g=(c>>3)&3, j=c&7; u = n*4 + (g^((n>>1)&3));
//   off = kt*8192 + u*8 + j
// H (LDS, 48x256): m,k -> g=k>>3; u = m*32 + (g ^ ((m>>1)&7))
// ---------------------------------------------------------------------------

// ---------------------------------------------------------------------------
// Column decode table: col -> (src scalar idx, freq, kind)
// kind: 0 raw, 1 sin, 2 cos, 3 zero.  enc = src | f<<5 | kind<<9
// ---------------------------------------------------------------------------
struct FT {
  u16 v[256];
  static constexpr u16 enc(int s, int f, int k) {
    return (u16)(s | (f << 5) | (k << 9));
  }
  constexpr void p3(int base, int F, int src) {
    v[base + 0] = enc(src + 0, 0, 0);
    v[base + 1] = enc(src + 1, 0, 0);
    v[base + 2] = enc(src + 2, 0, 0);
    for (int f = 0; f < F; ++f)
      for (int r = 0; r < 6; ++r) {
        int comp = (r < 3) ? r : r - 3;
        v[base + 3 + f * 6 + r] = enc(src + comp, f, (r < 3) ? 1 : 2);
      }
  }
  constexpr void p1(int base, int F, int src) {
    v[base] = enc(src, 0, 0);
    for (int f = 0; f < F; ++f) {
      v[base + 1 + 2 * f] = enc(src, f, 1);
      v[base + 2 + 2 * f] = enc(src, f, 2);
    }
  }
  constexpr FT() : v{} {
    p3(0, 10, 0);     // hit_pos_emb   (q)          [0..62]
    p1(63, 4, 3);     // density_emb                [63..71]
    p3(72, 10, 4);    // smoothed_emb  (sp)         [72..134]
    p3(135, 10, 7);   // var_emb       (var)        [135..197]
    p3(198, 4, 10);   // hit_dir_emb   (ray dir)    [198..224]
    p3(225, 4, 13);   // dirs_emb      (dir)        [225..251]
    v[252] = enc(16, 0, 0);  // normals
    v[253] = enc(17, 0, 0);
    v[254] = enc(18, 0, 0);
    v[255] = enc(0, 0, 3);   // pad col
  }
};
__constant__ FT ftab = FT();

// ---------------------------------------------------------------------------
// Uniform grid for ball query: 10x10x10 cells, cell size 0.1 = RADIUS.
// Coverage of the 3x3x3 neighborhood is exact: |dx|<0.1 implies cell delta
// in {-1,0,1} per axis. cid = (cz*10+cy)*10+cx, so an x-span is CONTIGUOUS
// in g_sorted -> 9 ranges per query. Order within cell arbitrary (selection
// is by index threshold, not storage order).
// ---------------------------------------------------------------------------
__device__ float4 g_sorted[4096];   // x,y,z, w = bitcast(original index)
__device__ int    g_cellStart[1001];

__global__ __launch_bounds__(1024) void build_grid(const float* __restrict__ parts)
{
  __shared__ int cnt[1000];
  __shared__ int pos[1000];
  __shared__ int wpre[125];
  const int tid = threadIdx.x;
  for (int j = tid; j < 1000; j += 1024) cnt[j] = 0;
  __syncthreads();

  float px[4], py[4], pz[4];
  int cd[4];
  #pragma unroll
  for (int t = 0; t < 4; ++t) {
    int i = tid + t * 1024;
    float x = parts[3 * i], y = parts[3 * i + 1], z = parts[3 * i + 2];
    int cx = min(max((int)(x * 10.0f), 0), 9);
    int cy = min(max((int)(y * 10.0f), 0), 9);
    int cz = min(max((int)(z * 10.0f), 0), 9);
    cd[t] = (cz * 10 + cy) * 10 + cx;
    px[t] = x; py[t] = y; pz[t] = z;
    atomicAdd(&cnt[cd[t]], 1);
  }
  __syncthreads();

  // hierarchical exclusive scan over 1000 cells: 125 x 8
  if (tid < 125) {
    int s = 0;
    #pragma unroll
    for (int k = 0; k < 8; ++k) s += cnt[tid * 8 + k];
    wpre[tid] = s;
  }
  __syncthreads();
  if (tid == 0) {
    int s = 0;
    for (int c = 0; c < 125; ++c) { int t = wpre[c]; wpre[c] = s; s += t; }
  }
  __syncthreads();
  if (tid < 125) {
    int run = wpre[tid];
    #pragma unroll
    for (int k = 0; k < 8; ++k) {
      int c = tid * 8 + k;
      int n = cnt[c];
      pos[c] = run;
      g_cellStart[c] = run;
      run += n;
    }
  }
  if (tid == 0) g_cellStart[1000] = 4096;
  __syncthreads();

  #pragma unroll
  for (int t = 0; t < 4; ++t) {
    int p = atomicAdd(&pos[cd[t]], 1);
    g_sorted[p] = make_float4(px[t], py[t], pz[t], __int_as_float(tid + t * 1024));
  }
}

// ---------------------------------------------------------------------------
// Kernel 1: weight prep fp32 -> fp16, BK=32 swizzled layout.
// ---------------------------------------------------------------------------
__global__ __launch_bounds__(256) void prep_weights(
    const float* __restrict__ W0, const float* __restrict__ W1,
    const float* __restrict__ W2,
    f16* __restrict__ w0f, f16* __restrict__ w1f, f16* __restrict__ w2f)
{
  int i = blockIdx.x * 256 + threadIdx.x;   // 0 .. 262143
  float v; f16* pf; int n, c;
  if (i < 131072) {
    n = i >> 9; c = i & 511;
    v = (c < 255) ? W0[n * 511 + c] : ((c == 255) ? 0.0f : W0[n * 511 + (c - 1)]);
    pf = w0f;
  } else if (i < 196608) {
    int j = i - 131072; n = j >> 8; c = j & 255; v = W1[j]; pf = w1f;
  } else {
    int j = i - 196608; n = j >> 8; c = j & 255; v = W2[j]; pf = w2f;
  }
  int kt = c >> 5, g = (c >> 3) & 3, jj = c & 7;
  int u = n * 4 + (g ^ ((n >> 1) & 3));
  pf[kt * 8192 + u * 8 + jj] = (f16)v;
}

// ---------------------------------------------------------------------------
// Kernel 2: grid-accelerated ball query + features -> swizzled fp16 X.
// 1 wave/query, 4 queries/block (load balance). 3x3x3 cell neighborhood as
// 9 contiguous ranges (~110 candidates). Range table via readlane -> SGPRs
// (no bpermute). First-16-by-index via binary-searched index threshold.
// Wave-uniform brute-scan fallback only if C > MAXCH*64 (never, in practice).
// ---------------------------------------------------------------------------
#define MAXCH 5   // up to 320 candidate slots per query (lambda ~110)

__global__ __launch_bounds__(256) void feat_kernel(
    const float* __restrict__ points, const float* __restrict__ normals,
    const float* __restrict__ parts, const float* __restrict__ rays,
    const float* __restrict__ ro, f16* __restrict__ Xf)
{
  __shared__ float sdata[4][20];

  const int tid = threadIdx.x;
  const int lane = tid & 63, wv = tid >> 6;
  const int q = blockIdx.x * 4 + wv;
  const float qx = points[3 * q], qy = points[3 * q + 1], qz = points[3 * q + 2];
  const float RQ = 0.1f * 0.1f;

  int nAcc = 0;
  float sdx = 0, sdy = 0, sdz = 0;
  float s2x = 0, s2y = 0, s2z = 0;
  float sw = 0, swx = 0, swy = 0, swz = 0;

  const int cqx = min(max((int)(qx * 10.0f), 0), 9);
  const int cqy = min(max((int)(qy * 10.0f), 0), 9);
  const int cqz = min(max((int)(qz * 10.0f), 0), 9);

  // lanes 0..8 each own one (cy,cz) row of the 3x3x3 neighborhood;
  // the x-span [x0..x1] is contiguous in g_sorted.
  int st_l = 0, cn_l = 0;
  if (lane < 9) {
    int dz = lane / 3, dy = lane - dz * 3;
    int cz = cqz - 1 + dz, cy = cqy - 1 + dy;
    if ((unsigned)cz <= 9u && (unsigned)cy <= 9u) {
      int x0 = max(cqx - 1, 0), x1 = min(cqx + 1, 9);
      int rb = (cz * 10 + cy) * 10;
      st_l = g_cellStart[rb + x0];
      cn_l = g_cellStart[rb + x1 + 1] - st_l;
    }
  }

  // range table to SGPRs; scalar prefix sum
  int pk[9], bk[9];
  int run = 0;
  #pragma unroll
  for (int k = 0; k < 9; ++k) {
    int stk = __builtin_amdgcn_readlane(st_l, k);
    int cnk = __builtin_amdgcn_readlane(cn_l, k);
    pk[k] = run;
    bk[k] = stk - run;
    run += cnk;
  }
  const int C = run;               // total candidates (wave-uniform)
  const bool fb = (C > MAXCH * 64);

  if (!fb) {
    float4 sv[MAXCH];
    int iv[MAXCH];
    unsigned long long hm[MAXCH];
    #pragma unroll
    for (int ch = 0; ch < MAXCH; ++ch) {
      if (ch * 64 < C) {           // wave-uniform guard
        int s = ch * 64 + lane;
        int g = bk[0];
        #pragma unroll
        for (int k = 1; k < 9; ++k) g = (s >= pk[k]) ? bk[k] : g;
        float4 pt = g_sorted[min(g + s, 4095)];
        if (s >= C) {              // sentinel: never hits, idx = +inf
          pt.x = 1e9f; pt.y = 1e9f; pt.z = 1e9f;
          pt.w = __int_as_float(0x7fffffff);
        }
        sv[ch] = pt;
        iv[ch] = __float_as_int(pt.w);
        float ex = pt.x - qx, ey = pt.y - qy, ez = pt.z - qz;
        float d2 = __fadd_rn(__fadd_rn(__fmul_rn(ex, ex), __fmul_rn(ey, ey)),
                             __fmul_rn(ez, ez));
        hm[ch] = __ballot(d2 < RQ);
      } else {
        hm[ch] = 0ULL;
      }
    }

    int N = 0;
    #pragma unroll
    for (int ch = 0; ch < MAXCH; ++ch) N += __popcll(hm[ch]);

    // threshold = 16th-smallest hit index (accept idx <= thr)
    int thr = 0x7fffffff;
    if (N > 16) {
      int lo = 0, hi = 4095;
      while (lo < hi) {
        int mid = (lo + hi) >> 1;
        int c = 0;
        #pragma unroll
        for (int ch = 0; ch < MAXCH; ++ch)
          if (ch * 64 < C)
            c += __popcll(hm[ch] & __ballot(iv[ch] <= mid));
        if (c >= 16) hi = mid; else lo = mid + 1;
      }
      thr = lo;
    }

    #pragma unroll
    for (int ch = 0; ch < MAXCH; ++ch) {
      if (ch * 64 < C) {
        float4 pt = sv[ch];
        float ex = pt.x - qx, ey = pt.y - qy, ez = pt.z - qz;
        float d2 = __fadd_rn(__fadd_rn(__fmul_rn(ex, ex), __fmul_rn(ey, ey)),
                             __fmul_rn(ez, ez));
        if (d2 < RQ && iv[ch] <= thr) {
          nAcc++;
          sdx += ex; sdy += ey; sdz += ez;
          s2x += ex * ex; s2y += ey * ey; s2z += ez * ez;
          float dn = sqrtf(d2);
          float t = dn * 10.0f;
          float w = fmaxf(1.0f - t * t * t, 0.0f);
          sw += w; swx += w * pt.x; swy += w * pt.y; swz += w * pt.z;
        }
      }
    }
  } else {
    // brute-force scan in index order (wave-uniform, effectively never taken)
    int total = 0;
    for (int jr = 0; jr < 64; ++jr) {
      int pi = jr * 64 + lane;
      float x = parts[3 * pi], y = parts[3 * pi + 1], z = parts[3 * pi + 2];
      float ex = x - qx, ey = y - qy, ez = z - qz;
      float d2 = __fadd_rn(__fadd_rn(__fmul_rn(ex, ex), __fmul_rn(ey, ey)),
                           __fmul_rn(ez, ez));
      bool hit = d2 < RQ;
      unsigned long long m = __ballot(hit);
      int pos = __builtin_amdgcn_mbcnt_hi((unsigned)(m >> 32),
                __builtin_amdgcn_mbcnt_lo((unsigned)m, 0u));
      if (hit && (total + pos < 16)) {
        nAcc++;
        sdx += ex; sdy += ey; sdz += ez;
        s2x += ex * ex; s2y += ey * ey; s2z += ez * ez;
        float dn = sqrtf(d2);
        float t = dn * 10.0f;
        float w = fmaxf(1.0f - t * t * t, 0.0f);
        sw += w; swx += w * x; swy += w * y; swz += w * z;
      }
      total += __popcll(m);
      if (total >= 16) break;
    }
  }

  #define WRED(x) { _Pragma("unroll") for (int o = 32; o; o >>= 1) x += __shfl_xor(x, o, 64); }
  float fn = (float)nAcc;
  WRED(fn); WRED(sdx); WRED(sdy); WRED(sdz);
  WRED(s2x); WRED(s2y); WRED(s2z);
  WRED(sw); WRED(swx); WRED(swy); WRED(swz);
  #undef WRED

  float tq = sqrtf(qx * qx + qy * qy + qz * qz) * 10.0f;
  float wpad = fmaxf(1.0f - tq * tq * tq, 0.0f);
  float density = sw + (16.0f - fn) * wpad;
  float invd = 1.0f / (density + 1e-12f);
  float spx = swx * invd, spy = swy * invd, spz = swz * invd;

  float invn = 1.0f / (fn + 1e-12f);
  float mx = sdx * invn, my = sdy * invn, mz = sdz * invn;
  float vx = fmaxf((s2x - 2.0f * mx * sdx + fn * mx * mx) * invn, 0.0f);
  float vy = fmaxf((s2y - 2.0f * my * sdy + fn * my * my) * invn, 0.0f);
  float vz = fmaxf((s2z - 2.0f * mz * sdz + fn * mz * mz) * invn, 0.0f);

  float dxx = spx - ro[0], dyy = spy - ro[1], dzz = spz - ro[2];
  float il = 1.0f / sqrtf(dxx * dxx + dyy * dyy + dzz * dzz);

  if (lane == 0) {
    float* s = sdata[wv];
    s[0] = qx; s[1] = qy; s[2] = qz; s[3] = density;
    s[4] = spx; s[5] = spy; s[6] = spz;
    s[7] = vx; s[8] = vy; s[9] = vz;
    int r = q / 48;
    s[10] = rays[6 * r + 3]; s[11] = rays[6 * r + 4]; s[12] = rays[6 * r + 5];
    s[13] = dxx * il; s[14] = dyy * il; s[15] = dzz * il;
    s[16] = normals[3 * q]; s[17] = normals[3 * q + 1]; s[18] = normals[3 * q + 2];
  }
  __syncthreads();

  const int b = q / 48, m48 = q % 48;
  const size_t base = (size_t)b * 12288;
  #pragma unroll
  for (int it = 0; it < 4; ++it) {
    int c = it * 64 + lane;
    int e = ftab.v[c];
    float sv_ = sdata[wv][e & 31];
    float arg = sv_ * (float)(1 << ((e >> 5) & 15));
    float sn, cs;
    sincosf(arg, &sn, &cs);
    int kind = e >> 9;
    float val = (kind == 0) ? sv_ : (kind == 1 ? sn : (kind == 2 ? cs : 0.0f));
    int kt = c >> 5, g = (c >> 3) & 3, j = c & 7;
    int u = m48 * 4 + (g ^ ((m48 >> 1) & 3));
    Xf[base + kt * 1536 + u * 8 + j] = (f16)val;
  }
}

// ---------------------------------------------------------------------------
// Kernel 3: fused 3-layer fp16 MFMA MLP + final 256->3 + sigmoid (unchanged).
// ---------------------------------------------------------------------------
__global__ __launch_bounds__(256, 2) void fused_mlp(
    const f16* __restrict__ Xf, const float* __restrict__ fvec,
    const f16* __restrict__ w0f, const f16* __restrict__ w1f,
    const f16* __restrict__ w2f,
    const float* __restrict__ b0, const float* __restrict__ b1,
    const float* __restrict__ b2,
    const float* __restrict__ W3, const float* __restrict__ b3,
    float* __restrict__ out)
{
  extern __shared__ char lds[];
  f16* Hf    = (f16*)lds;                 // 24576 B
  f16* Bs    = (f16*)(lds + 24576);       // 16384 B
  f16* Ah_st = (f16*)lds;                 // 3072 B (L0 only)
  float* w3s = (float*)(lds + 24576);

  const int tid = threadIdx.x, lane = tid & 63, wn = tid >> 6;
  const int l15 = lane & 15, l4 = lane >> 4;
  const int blk = blockIdx.x;

  if (blk & 1) __builtin_amdgcn_s_sleep(8);   // de-phase co-resident blocks

  f32x4 acc[3][4];

  const f16* Xft = Xf + (size_t)blk * 12288;

  auto stageB = [&](const f16* wf, int kt) {
    #pragma unroll
    for (int s = 0; s < 4; ++s) {
      int ch = wn + s * 4;                // 0..15, 1 KB chunks
      glds16(wf + kt * 8192 + ch * 512 + lane * 8, Bs + ch * 512 + lane * 8);
    }
  };
  auto stageA = [&](int kt) {
    if (kt < 8) {
      if (wn < 3)
        glds16(Xft + kt * 1536 + wn * 512 + lane * 8, Ah_st + wn * 512 + lane * 8);
    } else {
      if (tid < 192) {
        int m = tid >> 2, g = tid & 3;
        const float* src = fvec + (size_t)(blk * 48 + m) * 256 + (kt - 8) * 32 + g * 8;
        float4 v0 = ((const float4*)src)[0];
        float4 v1 = ((const float4*)src)[1];
        f16 hs[8] = {(f16)v0.x, (f16)v0.y, (f16)v0.z, (f16)v0.w,
                     (f16)v1.x, (f16)v1.y, (f16)v1.z, (f16)v1.w};
        int u = m * 4 + (g ^ ((m >> 1) & 3));
        *(uint4*)(Ah_st + u * 8) = *(uint4*)hs;
      }
    }
  };
  auto bfrags = [&](f16x8* bf) {
    #pragma unroll
    for (int j = 0; j < 4; ++j) {
      int n = wn * 64 + j * 16 + l15;
      int u = n * 4 + (l4 ^ ((n >> 1) & 3));
      bf[j] = __builtin_bit_cast(f16x8, *(const uint4*)(Bs + u * 8));
    }
  };
  auto mfmas = [&](f16x8* af, f16x8* bf) {
    #pragma unroll
    for (int i = 0; i < 3; ++i)
      #pragma unroll
      for (int j = 0; j < 4; ++j)
        acc[i][j] = __builtin_amdgcn_mfma_f32_16x16x32_f16(af[i], bf[j], acc[i][j], 0, 0, 0);
  };
  auto epilogue = [&](const float* bias_) {
    float bv[4];
    #pragma unroll
    for (int j = 0; j < 4; ++j) bv[j] = bias_[wn * 64 + j * 16 + l15];
    #pragma unroll
    for (int i = 0; i < 3; ++i) {
      #pragma unroll
      for (int r = 0; r < 4; ++r) {
        int m = i * 16 + l4 * 4 + r;
        #pragma unroll
        for (int j = 0; j < 4; ++j) {
          int n = wn * 64 + j * 16 + l15;
          float v = fmaxf(acc[i][j][r] + bv[j], 0.0f);
          int u = m * 32 + ((n >> 3) ^ ((m >> 1) & 7));
          Hf[u * 8 + (n & 7)] = (f16)v;
        }
      }
    }
  };

  // ======================= L0: K=512 (8 kt from X, 8 from fvec) ============
  #pragma unroll
  for (int i = 0; i < 3; ++i)
    #pragma unroll
    for (int j = 0; j < 4; ++j) acc[i][j] = (f32x4){0, 0, 0, 0};

  stageA(0);
  stageB(w0f, 0);
  for (int kt = 0; kt < 16; ++kt) {
    __syncthreads();                       // drain stage(kt)
    f16x8 af[3], bf[4];
    #pragma unroll
    for (int i = 0; i < 3; ++i) {
      int m = i * 16 + l15;
      int u = m * 4 + (l4 ^ ((m >> 1) & 3));
      af[i] = __builtin_bit_cast(f16x8, *(const uint4*)(Ah_st + u * 8));
    }
    bfrags(bf);
    __syncthreads();                       // all reads in regs
    if (kt < 15) { stageA(kt + 1); stageB(w0f, kt + 1); }
    mfmas(af, bf);
  }
  epilogue(b0);

  // ======================= L1, L2: K=256, A from Hf ========================
  #pragma unroll 1
  for (int layer = 0; layer < 2; ++layer) {
    const f16* wf = layer ? w2f : w1f;
    #pragma unroll
    for (int i = 0; i < 3; ++i)
      #pragma unroll
      for (int j = 0; j < 4; ++j) acc[i][j] = (f32x4){0, 0, 0, 0};

    stageB(wf, 0);
    for (int kt = 0; kt < 8; ++kt) {
      __syncthreads();                     // kt=0 also fences epilogue H writes
      f16x8 af[3], bf[4];
      #pragma unroll
      for (int i = 0; i < 3; ++i) {
        int m = i * 16 + l15;
        int g = kt * 4 + l4;
        int u = m * 32 + (g ^ ((m >> 1) & 7));
        af[i] = __builtin_bit_cast(f16x8, *(const uint4*)(Hf + u * 8));
      }
      bfrags(bf);
      __syncthreads();
      if (kt < 7) stageB(wf, kt + 1);
      mfmas(af, bf);
    }
    epilogue(layer ? b2 : b1);
  }

  // ======================= final: 256 -> 3 + sigmoid =======================
  __syncthreads();                         // H complete, B region free
  for (int i = tid; i < 768; i += 256) w3s[i] = W3[i];
  __syncthreads();

  const float B30 = b3[0], B31 = b3[1], B32 = b3[2];
  #pragma unroll 1
  for (int rr = 0; rr < 12; ++rr) {
    int m = wn * 12 + rr;
    int g = lane >> 1, j0 = (lane & 1) * 4;
    int u = m * 32 + (g ^ ((m >> 1) & 7));
    uint2 pk = *(const uint2*)(Hf + u * 8 + j0);
    f16 h4[4];
    *(uint2*)h4 = pk;
    float h0 = (float)h4[0], h1 = (float)h4[1], h2 = (float)h4[2], h3 = (float)h4[3];
    int kc = lane * 4;
    float4 wa = *(const float4*)(w3s + kc);
    float4 wb = *(const float4*)(w3s + 256 + kc);
    float4 wc = *(const float4*)(w3s + 512 + kc);
    float p0 = fmaf(h3, wa.w, fmaf(h2, wa.z, fmaf(h1, wa.y, h0 * wa.x)));
    float p1 = fmaf(h3, wb.w, fmaf(h2, wb.z, fmaf(h1, wb.y, h0 * wb.x)));
    float p2 = fmaf(h3, wc.w, fmaf(h2, wc.z, fmaf(h1, wc.y, h0 * wc.x)));
    #pragma unroll
    for (int o = 32; o; o >>= 1) {
      p0 += __shfl_xor(p0, o, 64);
      p1 += __shfl_xor(p1, o, 64);
      p2 += __shfl_xor(p2, o, 64);
    }
    if (lane == 0) {
      size_t ro_ = (size_t)(blk * 48 + m) * 3;
      out[ro_ + 0] = 1.0f / (1.0f + expf(-(p0 + B30)));
      out[ro_ + 1] = 1.0f / (1.0f + expf(-(p1 + B31)));
      out[ro_ + 2] = 1.0f / (1.0f + expf(-(p2 + B32)));
    }
  }
}

// ---------------------------------------------------------------------------
extern "C" void kernel_launch(void* const* d_in, const int* in_sizes, int n_in,
                              void* d_out, int out_size, void* d_ws, size_t ws_size,
                              hipStream_t stream) {
  const float* points  = (const float*)d_in[0];
  const float* normals = (const float*)d_in[1];
  const float* fvec    = (const float*)d_in[3];
  const float* parts   = (const float*)d_in[5];
  const float* rays    = (const float*)d_in[6];
  const float* ro      = (const float*)d_in[7];
  const float* W0 = (const float*)d_in[8];
  const float* b0 = (const float*)d_in[9];
  const float* W1 = (const float*)d_in[10];
  const float* b1 = (const float*)d_in[11];
  const float* W2 = (const float*)d_in[12];
  const float* b2 = (const float*)d_in[13];
  const float* W3 = (const float*)d_in[14];
  const float* b3 = (const float*)d_in[15];

  char* ws = (char*)d_ws;
  f16* Xf  = (f16*)(ws);                    // [24576,256] fp16 swizzled, 12.58 MB
  f16* w0f = (f16*)(ws + 12582912);         // 262144 B
  f16* w1f = (f16*)(ws + 12845056);         // 131072 B
  f16* w2f = (f16*)(ws + 12976128);         // 131072 B
  float* out = (float*)d_out;

  (void)hipFuncSetAttribute((const void*)fused_mlp,
                            hipFuncAttributeMaxDynamicSharedMemorySize, 40960);

  build_grid<<<1, 1024, 0, stream>>>(parts);
  prep_weights<<<1024, 256, 0, stream>>>(W0, W1, W2, w0f, w1f, w2f);
  feat_kernel<<<6144, 256, 0, stream>>>(points, normals, parts, rays, ro, Xf);
  fused_mlp<<<512, 256, 40960, stream>>>(Xf, fvec, w0f, w1f, w2f,
                                         b0, b1, b2, W3, b3, out);
}